// Round 2
// baseline (608.743 us; speedup 1.0000x reference)
//
#include <hip/hip_runtime.h>

// Problem constants
#define B_   32
#define N_   512
#define C_   768
#define H_   12
#define D_   64
#define HID_ 3072
#define BN_  (B_*N_)      // 16384 rows

typedef unsigned short u16;
typedef __attribute__((ext_vector_type(8))) short  short8;   // 8 bf16 (4 VGPRs)
typedef __attribute__((ext_vector_type(4))) float  float4v;  // 4 fp32 acc
typedef __attribute__((ext_vector_type(4))) int    int4v;

__device__ __forceinline__ u16 f32_to_bf16(float f) {
  unsigned u = __builtin_bit_cast(unsigned, f);
  u += 0x7fffu + ((u >> 16) & 1u);   // RNE
  return (u16)(u >> 16);
}

// async global->LDS, 16B per lane; lds base wave-uniform, lane i lands at base + i*16B
__device__ __forceinline__ void load_lds16(const u16* g, u16* l) {
  __builtin_amdgcn_global_load_lds(
      (const __attribute__((address_space(1))) unsigned int*)g,
      (__attribute__((address_space(3))) unsigned int*)l,
      16, 0, 0);
}

// inline-asm ds_read_b128: INVISIBLE to the compiler's waitcnt pass, so it cannot
// insert s_waitcnt vmcnt(0) before it for LDS-DMA aliasing (the round-1 stall).
// Caller MUST place s_waitcnt lgkmcnt(0) + sched_barrier(0) before consuming (rule #18).
__device__ __forceinline__ short8 ds_read_b128a(unsigned byte_off) {
  int4v r;
  asm volatile("ds_read_b128 %0, %1" : "=v"(r) : "v"(byte_off));
  return __builtin_bit_cast(short8, r);
}

__device__ __forceinline__ unsigned lds_addr(const u16* p) {
  return (unsigned)(size_t)(const __attribute__((address_space(3))) u16*)p;
}

// ---------------- weight cast f32 -> bf16 ----------------
__global__ void cast_kernel(const float* __restrict__ src, u16* __restrict__ dst, int n) {
  int i = blockIdx.x * 256 + threadIdx.x;
  if (i < n) dst[i] = f32_to_bf16(src[i]);
}

// ---------------- LayerNorm (row = 768 fp32) -> bf16 ----------------
__global__ __launch_bounds__(256)
void ln_kernel(const float* __restrict__ x, const float* __restrict__ w,
               const float* __restrict__ bias, u16* __restrict__ out) {
  const int row = blockIdx.x;
  const int tid = threadIdx.x;
  const float* xr = x + (size_t)row * C_;
  float v0 = xr[tid], v1 = xr[tid + 256], v2 = xr[tid + 512];
  float s = v0 + v1 + v2;
  float q = v0*v0 + v1*v1 + v2*v2;
#pragma unroll
  for (int off = 1; off < 64; off <<= 1) { s += __shfl_xor(s, off); q += __shfl_xor(q, off); }
  __shared__ float red[8];
  int wave = tid >> 6, lane = tid & 63;
  if (lane == 0) { red[wave] = s; red[4 + wave] = q; }
  __syncthreads();
  s = red[0] + red[1] + red[2] + red[3];
  q = red[4] + red[5] + red[6] + red[7];
  float mean = s * (1.0f / C_);
  float var  = q * (1.0f / C_) - mean * mean;
  float rstd = rsqrtf(var + 1e-5f);
  u16* orow = out + (size_t)row * C_;
  orow[tid]       = f32_to_bf16((v0 - mean) * rstd * w[tid]       + bias[tid]);
  orow[tid + 256] = f32_to_bf16((v1 - mean) * rstd * w[tid + 256] + bias[tid + 256]);
  orow[tid + 512] = f32_to_bf16((v2 - mean) * rstd * w[tid + 512] + bias[tid + 512]);
}

// ------- V transpose: qkv unified [BN, 3C] V-cols -> Vt[B*H, D, N] --------------
__global__ __launch_bounds__(256)
void transpose_v(const u16* __restrict__ qkv, u16* __restrict__ vt) {
  __shared__ alignas(16) u16 T[64 * 72];
  const int nt = blockIdx.x, bh = blockIdx.y;
  const int b = bh / H_, h = bh % H_;
  const int tid = threadIdx.x;
  const size_t rs3 = 3 * C_;
  const int r = tid >> 2, dc = (tid & 3) * 16;
  const u16* src = qkv + (size_t)(b * N_ + nt * 64 + r) * rs3 + 2 * C_ + h * D_ + dc;
  short8 a0 = *(const short8*)src;
  short8 a1 = *(const short8*)(src + 8);
#pragma unroll
  for (int j = 0; j < 8; j++) T[(dc + j) * 72 + r] = (u16)a0[j];
#pragma unroll
  for (int j = 0; j < 8; j++) T[(dc + 8 + j) * 72 + r] = (u16)a1[j];
  __syncthreads();
  const int d = tid >> 2, nc = (tid & 3) * 16;
  u16* dst = vt + ((size_t)(b * H_ + h) * D_ + d) * N_ + nt * 64 + nc;
  *(short8*)dst       = *(const short8*)&T[d * 72 + nc];
  *(short8*)(dst + 8) = *(const short8*)&T[d * 72 + nc + 8];
}

// ================= 128x128x(BK=64) bf16 NT GEMM (round-0 proven core) ============
// Used for qkv and proj (CONTROL arm of the structure A/B).
template <int EPI>
__device__ __forceinline__ void gemm_core128(const u16* __restrict__ A, const u16* __restrict__ W,
                                             int N, int K,
                                             const float* __restrict__ bias,
                                             const float* __restrict__ resid,
                                             u16* __restrict__ out_bf, float* __restrict__ out_f) {
  __shared__ alignas(16) u16 As[128 * 64];
  __shared__ alignas(16) u16 Ws[128 * 64];
  const int tid  = threadIdx.x;
  const int wave = tid >> 6;
  const int lane = tid & 63;
  const int quad = lane >> 4;
  const int l15  = lane & 15;

  const int nx    = gridDim.x;
  const int lin   = blockIdx.y * nx + blockIdx.x;
  const int total = nx * gridDim.y;
  const int v     = (lin & 7) * (total >> 3) + (lin >> 3);
  const int m0 = (v / nx) << 7;
  const int n0 = (v % nx) << 7;

  const int wm = (wave >> 1) * 64;
  const int wn = (wave & 1) * 64;

  float4v acc[4][4];
#pragma unroll
  for (int i = 0; i < 4; i++)
#pragma unroll
    for (int j = 0; j < 4; j++) acc[i][j] = (float4v){0.f, 0.f, 0.f, 0.f};

  const int c0   = wave * 4;
  const int srow = lane >> 3;
  const int gcol = ((lane & 7) ^ srow) * 8;
  const u16* Ag[4];
  const u16* Wg[4];
#pragma unroll
  for (int j = 0; j < 4; j++) {
    const int row = (c0 + j) * 8 + srow;
    Ag[j] = A + (size_t)(m0 + row) * K + gcol;
    Wg[j] = W + (size_t)(n0 + row) * K + gcol;
  }

  for (int k0 = 0; k0 < K; k0 += 64) {
    __syncthreads();
#pragma unroll
    for (int j = 0; j < 4; j++) load_lds16(Ag[j] + k0, &As[(c0 + j) * 512]);
#pragma unroll
    for (int j = 0; j < 4; j++) load_lds16(Wg[j] + k0, &Ws[(c0 + j) * 512]);
    __syncthreads();

    short8 af[4][2], bf[4][2];
#pragma unroll
    for (int mi = 0; mi < 4; mi++)
#pragma unroll
      for (int ks = 0; ks < 2; ks++) {
        const int swz = ((ks * 4 + quad) ^ (l15 & 7)) * 8;
        af[mi][ks] = *(const short8*)&As[(wm + mi * 16 + l15) * 64 + swz];
        bf[mi][ks] = *(const short8*)&Ws[(wn + mi * 16 + l15) * 64 + swz];
      }
#pragma unroll
    for (int ks = 0; ks < 2; ks++)
#pragma unroll
      for (int mi = 0; mi < 4; mi++)
#pragma unroll
        for (int ni = 0; ni < 4; ni++)
          acc[mi][ni] = __builtin_amdgcn_mfma_f32_16x16x32_bf16(af[mi][ks], bf[ni][ks], acc[mi][ni], 0, 0, 0);
  }

#pragma unroll
  for (int mi = 0; mi < 4; mi++) {
#pragma unroll
    for (int r = 0; r < 4; r++) {
      const int row = m0 + wm + mi * 16 + quad * 4 + r;
#pragma unroll
      for (int ni = 0; ni < 4; ni++) {
        const int col = n0 + wn + ni * 16 + l15;
        float v2 = acc[mi][ni][r];
        if (EPI == 0) {
          out_bf[(size_t)row * N + col] = f32_to_bf16(v2);
        } else if (EPI == 1) {
          v2 += bias[col];
          v2 = 0.5f * v2 * (1.0f + erff(v2 * 0.70710678118654752f));
          out_bf[(size_t)row * N + col] = f32_to_bf16(v2);
        } else if (EPI == 2) {
          out_f[(size_t)row * N + col] = 2.0f * (v2 + bias[col]);
        } else {
          out_f[(size_t)row * N + col] = v2 + bias[col] + resid[(size_t)row * N + col];
        }
      }
    }
  }
}

// ================= 256x256x(BK=64) bf16 NT GEMM, 8-phase counted-vmcnt v2 ========
// v2 change: loop ds_reads are inline-asm (compiler-invisible) so the waitcnt pass
// cannot insert vmcnt(0) drains before them (round-1 stall).  Explicit
// s_waitcnt lgkmcnt(0) + sched_barrier(0) after barrier #1 of each phase (rule #18).
// Stage ledger & counted vmcnt identical to round 1 (refcheck'd there).
#define SBAR()                                   \
  do {                                           \
    asm volatile("" ::: "memory");               \
    __builtin_amdgcn_s_barrier();                \
    asm volatile("" ::: "memory");               \
  } while (0)

#define WAITL()                                              \
  do {                                                       \
    asm volatile("s_waitcnt lgkmcnt(0)" ::: "memory");       \
    __builtin_amdgcn_sched_barrier(0);                       \
  } while (0)

#define STG_A(BUF, HH, KT)                                                    \
  do {                                                                        \
    const u16* _s = aS + (size_t)(HH) * 128 * (size_t)K + (size_t)(KT) * 64;  \
    load_lds16(_s, &LA[BUF][HH][wave * 1024]);                                \
    load_lds16(_s + 8 * (size_t)K, &LA[BUF][HH][wave * 1024 + 512]);          \
  } while (0)

#define STG_B(BUF, HH, KT)                                                    \
  do {                                                                        \
    const u16* _s = bS + (size_t)(HH) * 128 * (size_t)K + (size_t)(KT) * 64;  \
    load_lds16(_s, &LB[BUF][HH][wave * 1024]);                                \
    load_lds16(_s + 8 * (size_t)K, &LB[BUF][HH][wave * 1024 + 512]);          \
  } while (0)

// asm ds_reads; byte offsets precomputed (aT/bT per K-tile, rb/sw per lane)
#define RDA_(MI0)                                                               \
  do {                                                                          \
    _Pragma("unroll") for (int mi = 0; mi < 4; ++mi) {                          \
      af[mi][0] = ds_read_b128a(aT + ((((MI0) + mi) * 1024u + rb + sw0) << 1)); \
      af[mi][1] = ds_read_b128a(aT + ((((MI0) + mi) * 1024u + rb + sw1) << 1)); \
    }                                                                           \
  } while (0)

#define RDB_(DST, NI0)                                                          \
  do {                                                                          \
    _Pragma("unroll") for (int ni = 0; ni < 2; ++ni) {                          \
      DST[ni][0] = ds_read_b128a(bT + ((((NI0) + ni) * 1024u + rb + sw0) << 1));\
      DST[ni][1] = ds_read_b128a(bT + ((((NI0) + ni) * 1024u + rb + sw1) << 1));\
    }                                                                           \
  } while (0)

#define MM(MI0, NI0, BF)                                                      \
  do {                                                                        \
    __builtin_amdgcn_s_setprio(1);                                            \
    _Pragma("unroll") for (int ks = 0; ks < 2; ++ks)                          \
      _Pragma("unroll") for (int mi = 0; mi < 4; ++mi)                        \
        _Pragma("unroll") for (int ni = 0; ni < 2; ++ni)                      \
          acc[(MI0) + mi][(NI0) + ni] =                                       \
              __builtin_amdgcn_mfma_f32_16x16x32_bf16(                        \
                  af[mi][ks], BF[ni][ks], acc[(MI0) + mi][(NI0) + ni], 0, 0, 0);\
    __builtin_amdgcn_s_setprio(0);                                            \
    __builtin_amdgcn_sched_barrier(0);                                        \
  } while (0)

template <int EPI>
__device__ __forceinline__ void gemm256_core(const u16* __restrict__ A, const u16* __restrict__ W,
                                             int N, int K,
                                             const float* __restrict__ bias,
                                             const float* __restrict__ resid,
                                             u16* __restrict__ out_bf, float* __restrict__ out_f) {
  __shared__ alignas(16) u16 LA[2][2][8192];   // [buf][half][128*64]  64 KiB
  __shared__ alignas(16) u16 LB[2][2][8192];   //                      64 KiB
  const int tid  = threadIdx.x;
  const int wave = tid >> 6;
  const int lane = tid & 63;
  const int quad = lane >> 4;
  const int l15  = lane & 15;
  const int l7   = l15 & 7;
  const int wm   = wave >> 2;        // 0..1 -> M offset wm*128
  const int wn   = wave & 3;         // 0..3 -> N offset wn*64
  const int bhalf = wn >> 1;
  const int brow0 = (wn & 1) * 64;

  // XCD-aware bijective swizzle (all grids here are %8==0)
  const int nx    = gridDim.x;
  const int lin   = blockIdx.y * nx + blockIdx.x;
  const int total = nx * gridDim.y;
  const int v     = (lin & 7) * (total >> 3) + (lin >> 3);
  const int m0 = (v / nx) << 8;
  const int n0 = (v % nx) << 8;

  const int T = K >> 6;              // K-tiles

  float4v acc[8][4];
#pragma unroll
  for (int i = 0; i < 8; i++)
#pragma unroll
    for (int j = 0; j < 4; j++) acc[i][j] = (float4v){0.f, 0.f, 0.f, 0.f};

  // staging source (per lane)
  const int srow = lane >> 3;
  const int scol = ((lane & 7) ^ srow) << 3;
  const int rowc = wave * 16 + srow;
  const u16* aS = A + (size_t)(m0 + rowc) * K + scol;
  const u16* bS = W + (size_t)(n0 + rowc) * K + scol;

  // LDS byte-address bases for asm ds_reads
  const unsigned laBase = lds_addr(&LA[0][0][0]);
  const unsigned lbBase = lds_addr(&LB[0][0][0]);
  const unsigned sw0 = (unsigned)((quad ^ l7) << 3);
  const unsigned sw1 = (unsigned)(((4 + quad) ^ l7) << 3);
  const unsigned rb  = (unsigned)(l15 * 64);
  const unsigned aW  = laBase + (unsigned)(wm * 16384);              // + wm half
  const unsigned bW  = lbBase + (unsigned)(bhalf * 16384 + brow0 * 128);

  short8 af[4][2];
  short8 bf0[2][2];
  short8 bf1[2][2];

  // ---- prologue: t0 fully + t1.B halves; drain t0 (12 issued, leave 4) ----
  STG_A(0, 0, 0); STG_A(0, 1, 0);
  STG_B(0, 0, 0); STG_B(0, 1, 0);
  STG_B(1, 0, 1); STG_B(1, 1, 1);
  asm volatile("s_waitcnt vmcnt(4)" ::: "memory");
  SBAR();

  for (int kt = 0; kt < T; ++kt) {
    const int buf = kt & 1;
    const unsigned aT = aW + (unsigned)(buf * 32768);
    const unsigned bT = bW + (unsigned)(buf * 32768);
    // -------- phase 1: (M0,N0); stage t+1.A0 -> other buf --------
    RDA_(0);
    RDB_(bf0, 0);
    if (kt + 1 < T) STG_A(buf ^ 1, 0, kt + 1);
    SBAR();
    WAITL();
    MM(0, 0, bf0);
    SBAR();
    // -------- phase 2: (M0,N1); stage t+1.A1 --------
    RDB_(bf1, 2);
    if (kt + 1 < T) STG_A(buf ^ 1, 1, kt + 1);
    SBAR();
    WAITL();
    MM(0, 2, bf1);
    SBAR();
    // -------- phase 3: (M1,N0); B(buf) fully read after ph2 -> stage t+2.B0 --------
    RDA_(4);
    if (kt + 2 < T) STG_B(buf, 0, kt + 2);
    SBAR();
    WAITL();
    MM(4, 0, bf0);
    SBAR();
    // -------- phase 4: (M1,N1); stage t+2.B1; counted vmcnt then barrier --------
    if (kt + 2 < T) STG_B(buf, 1, kt + 2);
    SBAR();
    WAITL();
    MM(4, 2, bf1);
    if (kt >= T - 2) { asm volatile("s_waitcnt vmcnt(0)" ::: "memory"); }
    else             { asm volatile("s_waitcnt vmcnt(4)" ::: "memory"); }
    SBAR();
  }

  // ---- epilogue ----
#pragma unroll
  for (int mi = 0; mi < 8; ++mi) {
#pragma unroll
    for (int r = 0; r < 4; ++r) {
      const int row = m0 + wm * 128 + mi * 16 + quad * 4 + r;
#pragma unroll
      for (int ni = 0; ni < 4; ++ni) {
        const int col = n0 + wn * 64 + ni * 16 + l15;
        float v2 = acc[mi][ni][r];
        if (EPI == 0) {
          out_bf[(size_t)row * N + col] = f32_to_bf16(v2);
        } else if (EPI == 1) {
          v2 += bias[col];
          v2 = 0.5f * v2 * (1.0f + erff(v2 * 0.70710678118654752f));
          out_bf[(size_t)row * N + col] = f32_to_bf16(v2);
        } else if (EPI == 2) {
          out_f[(size_t)row * N + col] = 2.0f * (v2 + bias[col]);
        } else {
          out_f[(size_t)row * N + col] = v2 + bias[col] + resid[(size_t)row * N + col];
        }
      }
    }
  }
}

#undef SBAR
#undef WAITL
#undef STG_A
#undef STG_B
#undef RDA_
#undef RDB_
#undef MM

// control arm: proven 128^2 core
__global__ __launch_bounds__(256, 3)
void gemm_qkv(const u16* __restrict__ A, const u16* __restrict__ W, int N, int K,
              u16* __restrict__ out_bf) {
  gemm_core128<0>(A, W, N, K, nullptr, nullptr, out_bf, nullptr);
}
__global__ __launch_bounds__(256, 3)
void gemm_proj2x(const u16* __restrict__ A, const u16* __restrict__ W, int N, int K,
                 const float* __restrict__ bias, float* __restrict__ out_f) {
  gemm_core128<2>(A, W, N, K, bias, nullptr, nullptr, out_f);
}
// treatment arm: 8-phase v2
__global__ __launch_bounds__(512, 2)
void gemm_fc1gelu(const u16* __restrict__ A, const u16* __restrict__ W, int N, int K,
                  const float* __restrict__ bias, u16* __restrict__ out_bf) {
  gemm256_core<1>(A, W, N, K, bias, nullptr, out_bf, nullptr);
}
__global__ __launch_bounds__(512, 2)
void gemm_fc2res(const u16* __restrict__ A, const u16* __restrict__ W, int N, int K,
                 const float* __restrict__ bias, const float* __restrict__ resid,
                 float* __restrict__ out_f) {
  gemm256_core<3>(A, W, N, K, bias, resid, nullptr, out_f);
}

// ---------------- flash attention v3 ---------------------------------------------
__global__ __launch_bounds__(256)
void attn_kernel(const u16* __restrict__ qkv, const u16* __restrict__ vt,
                 u16* __restrict__ o) {
  __shared__ alignas(16) u16 Ks[64 * 64];
  __shared__ alignas(16) u16 Vs[64 * 64];
  __shared__ alignas(16) u16 Ps[8][16 * 64];
  const int tid  = threadIdx.x;
  const int wave = tid >> 6, lane = tid & 63;
  const int quad = lane >> 4, l15 = lane & 15;
  const int lin = blockIdx.x;
  const int bh = lin % 384, qt = lin / 384;
  const int b = bh / H_, h = bh % H_;
  const size_t rs3 = 3 * C_;

  short8 qf[2][2];
#pragma unroll
  for (int st = 0; st < 2; st++) {
    const int qrow = b * N_ + qt * 128 + st * 64 + wave * 16 + l15;
    const u16* qp = qkv + (size_t)qrow * rs3 + h * D_ + quad * 8;
    qf[st][0] = *(const short8*)qp;
    qf[st][1] = *(const short8*)(qp + 32);
  }

  const int srow = lane >> 3;
  const int gcol = ((lane & 7) ^ srow) * 8;
  const int ch0 = wave * 2, ch1 = wave * 2 + 1;
  const u16* kg0 = qkv + (size_t)(b * N_ + ch0 * 8 + srow) * rs3 + C_ + h * D_ + gcol;
  const u16* kg1 = qkv + (size_t)(b * N_ + ch1 * 8 + srow) * rs3 + C_ + h * D_ + gcol;
  const u16* vg0 = vt + ((size_t)bh * D_ + ch0 * 8 + srow) * N_ + gcol;
  const u16* vg1 = vt + ((size_t)bh * D_ + ch1 * 8 + srow) * N_ + gcol;

  float m[2][4], l[2][4];
  float4v oacc[2][4];
#pragma unroll
  for (int st = 0; st < 2; st++)
#pragma unroll
    for (int r = 0; r < 4; r++) { m[st][r] = -1e30f; l[st][r] = 0.f; }
#pragma unroll
  for (int st = 0; st < 2; st++)
#pragma unroll
    for (int ni = 0; ni < 4; ni++) oacc[st][ni] = (float4v){0.f, 0.f, 0.f, 0.f};

  for (int kt = 0; kt < 8; ++kt) {
    __syncthreads();
    load_lds16(kg0 + (size_t)(kt * 64) * rs3, &Ks[ch0 * 512]);
    load_lds16(kg1 + (size_t)(kt * 64) * rs3, &Ks[ch1 * 512]);
    load_lds16(vg0 + kt * 64, &Vs[ch0 * 512]);
    load_lds16(vg1 + kt * 64, &Vs[ch1 * 512]);
    __syncthreads();

    short8 kf[4][2];
#pragma unroll
    for (int ni = 0; ni < 4; ni++)
#pragma unroll
      for (int ks = 0; ks < 2; ks++)
        kf[ni][ks] = *(const short8*)&Ks[(ni * 16 + l15) * 64 + ((ks * 4 + quad) ^ (l15 & 7)) * 8];

#pragma unroll
    for (int st = 0; st < 2; st++) {
      u16* myPs = Ps[wave * 2 + st];
      float4v s[4];
#pragma unroll
      for (int ni = 0; ni < 4; ni++) {
        s[ni] = (float4v){0.f, 0.f, 0.f, 0.f};
        s[ni] = __builtin_amdgcn_mfma_f32_16x16x32_bf16(qf[st][0], kf[ni][0], s[ni], 0, 0, 0);
        s[ni] = __builtin_amdgcn_mfma_f32_16x16x32_bf16(qf[st][1], kf[ni][1], s[ni], 0, 0, 0);
      }

      float mt[4];
#pragma unroll
      for (int r = 0; r < 4; r++)
        mt[r] = 0.125f * fmaxf(fmaxf(s[0][r], s[1][r]), fmaxf(s[2][r], s[3][r]));
#pragma unroll
      for (int off = 1; off < 16; off <<= 1)
#pragma unroll
        for (int r = 0; r < 4; r++) mt[r] = fmaxf(mt[r], __shfl_xor(mt[r], off));

      float alpha[4], mnew[4], rsum[4];
#pragma unroll
      for (int r = 0; r < 4; r++) {
        mnew[r] = fmaxf(m[st][r], mt[r]);
        alpha[r] = __expf(m[st][r] - mnew[r]);
        rsum[r] = 0.f;
      }
#pragma unroll
      for (int ni = 0; ni < 4; ni++)
#pragma unroll
        for (int r = 0; r < 4; r++) {
          float p = __expf(s[ni][r] * 0.125f - mnew[r]);
          rsum[r] += p;
          const int prow = quad * 4 + r;
          const int g = (ni * 2 + (l15 >> 3)) ^ (prow & 7);
          myPs[prow * 64 + g * 8 + (l15 & 7)] = f32_to_bf16(p);
        }
#pragma unroll
      for (int off = 1; off < 16; off <<= 1)
#pragma unroll
        for (int r = 0; r < 4; r++) rsum[r] += __shfl_xor(rsum[r], off);
#pragma unroll
      for (int r = 0; r < 4; r++) { l[st][r] = l[st][r] * alpha[r] + rsum[r]; m[st][r] = mnew[r]; }
#pragma unroll
      for (int ni = 0; ni < 4; ni++)
#pragma unroll
        for (int r = 0; r < 4; r++) oacc[st][ni][r] *= alpha[r];

#pragma unroll
      for (int ks = 0; ks < 2; ks++) {
        const int g = (ks * 4 + quad) ^ (l15 & 7);
        short8 pf = *(const short8*)&myPs[l15 * 64 + g * 8];
#pragma unroll
        for (int ni = 0; ni < 4; ni++) {
          short8 vf = *(const short8*)&Vs[(ni * 16 + l15) * 64 + ((ks * 4 + quad) ^ (l15 & 7)) * 8];
          oacc[st][ni] = __builtin_amdgcn_mfma_f32_16x16x32_bf16(pf, vf, oacc[st][ni], 0, 0, 0);
        }
      }
    }
  }

#pragma unroll
  for (int st = 0; st < 2; st++) {
    float inv[4];
#pragma unroll
    for (int r = 0; r < 4; r++) inv[r] = 1.0f / l[st][r];
#pragma unroll
    for (int ni = 0; ni < 4; ni++)
#pragma unroll
      for (int r = 0; r < 4; r++) {
        int row = b * N_ + qt * 128 + st * 64 + wave * 16 + quad * 4 + r;
        int col = h * D_ + ni * 16 + l15;
        o[(size_t)row * C_ + col] = f32_to_bf16(oacc[st][ni][r] * inv[r]);
      }
  }
}

// ---------------- launch ----------------
extern "C" void kernel_launch(void* const* d_in, const int* in_sizes, int n_in,
                              void* d_out, int out_size, void* d_ws, size_t ws_size,
                              hipStream_t stream) {
  const float* x      = (const float*)d_in[0];
  const float* ln1_w  = (const float*)d_in[1];
  const float* ln1_b  = (const float*)d_in[2];
  const float* qkv_w  = (const float*)d_in[3];
  const float* proj_w = (const float*)d_in[4];
  const float* proj_b = (const float*)d_in[5];
  const float* ln2_w  = (const float*)d_in[6];
  const float* ln2_b  = (const float*)d_in[7];
  const float* fc1_w  = (const float*)d_in[8];
  const float* fc1_b  = (const float*)d_in[9];
  const float* fc2_w  = (const float*)d_in[10];
  const float* fc2_b  = (const float*)d_in[11];
  float* out = (float*)d_out;

  char* ws = (char*)d_ws;
  size_t off = 0;
  auto alloc = [&](size_t bytes) { void* p = ws + off; off += (bytes + 255) & ~255ull; return p; };
  u16* wqkv  = (u16*)alloc((size_t)3 * C_ * C_ * 2);
  u16* wproj = (u16*)alloc((size_t)C_ * C_ * 2);
  u16* wfc1  = (u16*)alloc((size_t)HID_ * C_ * 2);
  u16* wfc2  = (u16*)alloc((size_t)C_ * HID_ * 2);
  u16* regionA = (u16*)alloc((size_t)BN_ * HID_ * 2);  // h | qkv, later o, later act
  float* xnew  = (float*)alloc((size_t)BN_ * C_ * 4);
  u16* h2      = (u16*)alloc((size_t)BN_ * C_ * 2);

  u16* hbuf = regionA;                        // [BN, C]   (dead after QKV)
  u16* qkvb = regionA + (size_t)BN_ * C_;     // [BN, 3C]  (dead after attn)
  u16* obuf = regionA;                        // [BN, C]   overwrites hbuf
  u16* act  = regionA;                        // [BN, HID] overwrites qkv+o
  u16* vtbuf = (u16*)xnew;                    // [B*H, D, N] aliases xnew (dead before proj writes)

  cast_kernel<<<dim3(3 * C_ * C_ / 256), 256, 0, stream>>>(qkv_w, wqkv, 3 * C_ * C_);
  cast_kernel<<<dim3(C_ * C_ / 256), 256, 0, stream>>>(proj_w, wproj, C_ * C_);
  cast_kernel<<<dim3(HID_ * C_ / 256), 256, 0, stream>>>(fc1_w, wfc1, HID_ * C_);
  cast_kernel<<<dim3(HID_ * C_ / 256), 256, 0, stream>>>(fc2_w, wfc2, C_ * HID_);

  ln_kernel<<<dim3(BN_), 256, 0, stream>>>(x, ln1_w, ln1_b, hbuf);

  gemm_qkv<<<dim3(3 * C_ / 128, BN_ / 128), 256, 0, stream>>>(hbuf, wqkv, 3 * C_, C_, qkvb);

  transpose_v<<<dim3(N_ / 64, B_ * H_), 256, 0, stream>>>(qkvb, vtbuf);

  attn_kernel<<<dim3((N_ / 128) * B_ * H_), 256, 0, stream>>>(qkvb, vtbuf, obuf);

  gemm_proj2x<<<dim3(C_ / 128, BN_ / 128), 256, 0, stream>>>(obuf, wproj, C_, C_, proj_b, xnew);

  ln_kernel<<<dim3(BN_), 256, 0, stream>>>(xnew, ln2_w, ln2_b, h2);

  gemm_fc1gelu<<<dim3(HID_ / 256, BN_ / 256), 512, 0, stream>>>(h2, wfc1, HID_, C_, fc1_b, act);

  gemm_fc2res<<<dim3(C_ / 256, BN_ / 256), 512, 0, stream>>>(act, wfc2, C_, HID_, fc2_b, xnew, out);
}

// Round 3
// 566.669 us; speedup vs baseline: 1.0742x; 1.0742x over previous
//
#include <hip/hip_runtime.h>

// Problem constants
#define B_   32
#define N_   512
#define C_   768
#define H_   12
#define D_   64
#define HID_ 3072
#define BN_  (B_*N_)      // 16384 rows

typedef unsigned short u16;
typedef __attribute__((ext_vector_type(8))) short  short8;   // 8 bf16 (4 VGPRs)
typedef __attribute__((ext_vector_type(4))) float  float4v;  // 4 fp32 acc
typedef __attribute__((ext_vector_type(4))) int    int4v;

__device__ __forceinline__ u16 f32_to_bf16(float f) {
  unsigned u = __builtin_bit_cast(unsigned, f);
  u += 0x7fffu + ((u >> 16) & 1u);   // RNE
  return (u16)(u >> 16);
}

// exact-GELU via A&S 7.1.26 erf approx, |err| < 1.5e-7 (below bf16 ulp).
// ~15 VALU vs libm erff's ~40 (dual-path + branches).
__device__ __forceinline__ float gelu_f(float x) {
  float z = fabsf(x) * 0.70710678118654752f;
  float t = __builtin_amdgcn_rcpf(1.0f + 0.3275911f * z);
  float p = t * (0.254829592f +
            t * (-0.284496736f +
            t * (1.421413741f +
            t * (-1.453152027f +
            t * 1.061405429f))));
  float e = __expf(-z * z);
  float er = 1.0f - p * e;                 // erf(z)
  er = (x < 0.0f) ? -er : er;
  return 0.5f * x * (1.0f + er);
}

// async global->LDS, 16B per lane; lds base wave-uniform, lane i lands at base + i*16B
__device__ __forceinline__ void load_lds16(const u16* g, u16* l) {
  __builtin_amdgcn_global_load_lds(
      (const __attribute__((address_space(1))) unsigned int*)g,
      (__attribute__((address_space(3))) unsigned int*)l,
      16, 0, 0);
}

// inline-asm ds_read_b128 (invisible to the waitcnt pass; caller pairs with
// s_waitcnt lgkmcnt(0) + sched_barrier(0) before use -- rule #18).
__device__ __forceinline__ short8 ds_read_b128a(unsigned byte_off) {
  int4v r;
  asm volatile("ds_read_b128 %0, %1" : "=v"(r) : "v"(byte_off));
  return __builtin_bit_cast(short8, r);
}

__device__ __forceinline__ unsigned lds_addr(const u16* p) {
  return (unsigned)(size_t)(const __attribute__((address_space(3))) u16*)p;
}

// ---------------- merged weight cast f32 -> bf16 (dst buffers are contiguous) ----
#define NW0_ (3 * C_ * C_)                 // 1769472
#define NW1_ (NW0_ + C_ * C_)              // 2359296
#define NW2_ (NW1_ + HID_ * C_)            // 4718592
#define NW3_ (NW2_ + C_ * HID_)            // 7077888
__global__ __launch_bounds__(256)
void cast4_kernel(const float* __restrict__ s0, const float* __restrict__ s1,
                  const float* __restrict__ s2, const float* __restrict__ s3,
                  u16* __restrict__ dst) {
  int i = blockIdx.x * 256 + threadIdx.x;
  const float* s; int j;
  if (i < NW0_)      { s = s0; j = i; }
  else if (i < NW1_) { s = s1; j = i - NW0_; }
  else if (i < NW2_) { s = s2; j = i - NW1_; }
  else               { s = s3; j = i - NW2_; }
  dst[i] = f32_to_bf16(s[j]);
}

// ---------------- LayerNorm (row = 768 fp32) -> bf16 ----------------
__global__ __launch_bounds__(256)
void ln_kernel(const float* __restrict__ x, const float* __restrict__ w,
               const float* __restrict__ bias, u16* __restrict__ out) {
  const int row = blockIdx.x;
  const int tid = threadIdx.x;
  const float* xr = x + (size_t)row * C_;
  float v0 = xr[tid], v1 = xr[tid + 256], v2 = xr[tid + 512];
  float s = v0 + v1 + v2;
  float q = v0*v0 + v1*v1 + v2*v2;
#pragma unroll
  for (int off = 1; off < 64; off <<= 1) { s += __shfl_xor(s, off); q += __shfl_xor(q, off); }
  __shared__ float red[8];
  int wave = tid >> 6, lane = tid & 63;
  if (lane == 0) { red[wave] = s; red[4 + wave] = q; }
  __syncthreads();
  s = red[0] + red[1] + red[2] + red[3];
  q = red[4] + red[5] + red[6] + red[7];
  float mean = s * (1.0f / C_);
  float var  = q * (1.0f / C_) - mean * mean;
  float rstd = rsqrtf(var + 1e-5f);
  u16* orow = out + (size_t)row * C_;
  orow[tid]       = f32_to_bf16((v0 - mean) * rstd * w[tid]       + bias[tid]);
  orow[tid + 256] = f32_to_bf16((v1 - mean) * rstd * w[tid + 256] + bias[tid + 256]);
  orow[tid + 512] = f32_to_bf16((v2 - mean) * rstd * w[tid + 512] + bias[tid + 512]);
}

// ------- V transpose: qkv unified [BN, 3C] V-cols -> Vt[B*H, D, N] --------------
__global__ __launch_bounds__(256)
void transpose_v(const u16* __restrict__ qkv, u16* __restrict__ vt) {
  __shared__ alignas(16) u16 T[64 * 72];
  const int nt = blockIdx.x, bh = blockIdx.y;
  const int b = bh / H_, h = bh % H_;
  const int tid = threadIdx.x;
  const size_t rs3 = 3 * C_;
  const int r = tid >> 2, dc = (tid & 3) * 16;
  const u16* src = qkv + (size_t)(b * N_ + nt * 64 + r) * rs3 + 2 * C_ + h * D_ + dc;
  short8 a0 = *(const short8*)src;
  short8 a1 = *(const short8*)(src + 8);
#pragma unroll
  for (int j = 0; j < 8; j++) T[(dc + j) * 72 + r] = (u16)a0[j];
#pragma unroll
  for (int j = 0; j < 8; j++) T[(dc + 8 + j) * 72 + r] = (u16)a1[j];
  __syncthreads();
  const int d = tid >> 2, nc = (tid & 3) * 16;
  u16* dst = vt + ((size_t)(b * H_ + h) * D_ + d) * N_ + nt * 64 + nc;
  *(short8*)dst       = *(const short8*)&T[d * 72 + nc];
  *(short8*)(dst + 8) = *(const short8*)&T[d * 72 + nc + 8];
}

// ================= 128x128x(BK=64) bf16 NT GEMM (round-0 proven core) ============
// CONTROL arm: qkv, proj, fc1.
template <int EPI>
__device__ __forceinline__ void gemm_core128(const u16* __restrict__ A, const u16* __restrict__ W,
                                             int N, int K,
                                             const float* __restrict__ bias,
                                             const float* __restrict__ resid,
                                             u16* __restrict__ out_bf, float* __restrict__ out_f) {
  __shared__ alignas(16) u16 As[128 * 64];
  __shared__ alignas(16) u16 Ws[128 * 64];
  const int tid  = threadIdx.x;
  const int wave = tid >> 6;
  const int lane = tid & 63;
  const int quad = lane >> 4;
  const int l15  = lane & 15;

  const int nx    = gridDim.x;
  const int lin   = blockIdx.y * nx + blockIdx.x;
  const int total = nx * gridDim.y;
  const int v     = (lin & 7) * (total >> 3) + (lin >> 3);
  const int m0 = (v / nx) << 7;
  const int n0 = (v % nx) << 7;

  const int wm = (wave >> 1) * 64;
  const int wn = (wave & 1) * 64;

  float4v acc[4][4];
#pragma unroll
  for (int i = 0; i < 4; i++)
#pragma unroll
    for (int j = 0; j < 4; j++) acc[i][j] = (float4v){0.f, 0.f, 0.f, 0.f};

  const int c0   = wave * 4;
  const int srow = lane >> 3;
  const int gcol = ((lane & 7) ^ srow) * 8;
  const u16* Ag[4];
  const u16* Wg[4];
#pragma unroll
  for (int j = 0; j < 4; j++) {
    const int row = (c0 + j) * 8 + srow;
    Ag[j] = A + (size_t)(m0 + row) * K + gcol;
    Wg[j] = W + (size_t)(n0 + row) * K + gcol;
  }

  for (int k0 = 0; k0 < K; k0 += 64) {
    __syncthreads();
#pragma unroll
    for (int j = 0; j < 4; j++) load_lds16(Ag[j] + k0, &As[(c0 + j) * 512]);
#pragma unroll
    for (int j = 0; j < 4; j++) load_lds16(Wg[j] + k0, &Ws[(c0 + j) * 512]);
    __syncthreads();

    short8 af[4][2], bf[4][2];
#pragma unroll
    for (int mi = 0; mi < 4; mi++)
#pragma unroll
      for (int ks = 0; ks < 2; ks++) {
        const int swz = ((ks * 4 + quad) ^ (l15 & 7)) * 8;
        af[mi][ks] = *(const short8*)&As[(wm + mi * 16 + l15) * 64 + swz];
        bf[mi][ks] = *(const short8*)&Ws[(wn + mi * 16 + l15) * 64 + swz];
      }
#pragma unroll
    for (int ks = 0; ks < 2; ks++)
#pragma unroll
      for (int mi = 0; mi < 4; mi++)
#pragma unroll
        for (int ni = 0; ni < 4; ni++)
          acc[mi][ni] = __builtin_amdgcn_mfma_f32_16x16x32_bf16(af[mi][ks], bf[ni][ks], acc[mi][ni], 0, 0, 0);
  }

#pragma unroll
  for (int mi = 0; mi < 4; mi++) {
#pragma unroll
    for (int r = 0; r < 4; r++) {
      const int row = m0 + wm + mi * 16 + quad * 4 + r;
#pragma unroll
      for (int ni = 0; ni < 4; ni++) {
        const int col = n0 + wn + ni * 16 + l15;
        float v2 = acc[mi][ni][r];
        if (EPI == 0) {
          out_bf[(size_t)row * N + col] = f32_to_bf16(v2);
        } else if (EPI == 1) {
          out_bf[(size_t)row * N + col] = f32_to_bf16(gelu_f(v2 + bias[col]));
        } else if (EPI == 2) {
          out_f[(size_t)row * N + col] = 2.0f * (v2 + bias[col]);
        } else {
          out_f[(size_t)row * N + col] = v2 + bias[col] + resid[(size_t)row * N + col];
        }
      }
    }
  }
}

// ======== 256x256x(BK=64) 8-phase v3': FULL-TILE-EARLY staging, vmcnt(8) =========
// TREATMENT arm (fc2res only this round).
// v3' change vs round 2: tile t stages ALL of tile t+2 (A0,A1,B0,B1 = 8 loads) in
// phase 4, after phase-3's barrier (by which every wave's reads of buf are done --
// race-free by full barrier separation).  End-of-tile wait is vmcnt(8): it drains
// tile t+1's loads, which were issued ONE FULL TILE earlier (~4 phases of slack vs
// round-2's 2-3 short phases) -- HBM latency fully hidden.  Registers identical to
// round 2 (af[4][2] reused for M1 via re-read in phase 3).
#define SBAR()                                   \
  do {                                           \
    asm volatile("" ::: "memory");               \
    __builtin_amdgcn_s_barrier();                \
    asm volatile("" ::: "memory");               \
  } while (0)

#define WAITL()                                              \
  do {                                                       \
    asm volatile("s_waitcnt lgkmcnt(0)" ::: "memory");       \
    __builtin_amdgcn_sched_barrier(0);                       \
  } while (0)

#define STG_A(BUF, HH, KT)                                                    \
  do {                                                                        \
    const u16* _s = aS + (size_t)(HH) * 128 * (size_t)K + (size_t)(KT) * 64;  \
    load_lds16(_s, &LA[BUF][HH][wave * 1024]);                                \
    load_lds16(_s + 8 * (size_t)K, &LA[BUF][HH][wave * 1024 + 512]);          \
  } while (0)

#define STG_B(BUF, HH, KT)                                                    \
  do {                                                                        \
    const u16* _s = bS + (size_t)(HH) * 128 * (size_t)K + (size_t)(KT) * 64;  \
    load_lds16(_s, &LB[BUF][HH][wave * 1024]);                                \
    load_lds16(_s + 8 * (size_t)K, &LB[BUF][HH][wave * 1024 + 512]);          \
  } while (0)

#define RD_A(MI0)                                                               \
  do {                                                                          \
    _Pragma("unroll") for (int mi = 0; mi < 4; ++mi) {                          \
      af[mi][0] = ds_read_b128a(aT + ((((MI0) + mi) * 1024u + rb + sw0) << 1)); \
      af[mi][1] = ds_read_b128a(aT + ((((MI0) + mi) * 1024u + rb + sw1) << 1)); \
    }                                                                           \
  } while (0)

#define RD_B(DST, NI0)                                                          \
  do {                                                                          \
    _Pragma("unroll") for (int ni = 0; ni < 2; ++ni) {                          \
      DST[ni][0] = ds_read_b128a(bT + ((((NI0) + ni) * 1024u + rb + sw0) << 1));\
      DST[ni][1] = ds_read_b128a(bT + ((((NI0) + ni) * 1024u + rb + sw1) << 1));\
    }                                                                           \
  } while (0)

#define MM(MI0, NI0, BF)                                                      \
  do {                                                                        \
    __builtin_amdgcn_s_setprio(1);                                            \
    _Pragma("unroll") for (int ks = 0; ks < 2; ++ks)                          \
      _Pragma("unroll") for (int mi = 0; mi < 4; ++mi)                        \
        _Pragma("unroll") for (int ni = 0; ni < 2; ++ni)                      \
          acc[(MI0) + mi][(NI0) + ni] =                                       \
              __builtin_amdgcn_mfma_f32_16x16x32_bf16(                        \
                  af[mi][ks], BF[ni][ks], acc[(MI0) + mi][(NI0) + ni], 0, 0, 0);\
    __builtin_amdgcn_s_setprio(0);                                            \
    __builtin_amdgcn_sched_barrier(0);                                        \
  } while (0)

template <int EPI>
__device__ __forceinline__ void gemm256_core(const u16* __restrict__ A, const u16* __restrict__ W,
                                             int N, int K,
                                             const float* __restrict__ bias,
                                             const float* __restrict__ resid,
                                             u16* __restrict__ out_bf, float* __restrict__ out_f) {
  __shared__ alignas(16) u16 LA[2][2][8192];   // [buf][half][128*64]  64 KiB
  __shared__ alignas(16) u16 LB[2][2][8192];   //                      64 KiB
  const int tid  = threadIdx.x;
  const int wave = tid >> 6;
  const int lane = tid & 63;
  const int quad = lane >> 4;
  const int l15  = lane & 15;
  const int l7   = l15 & 7;
  const int wm   = wave >> 2;        // 0..1 -> M offset wm*128
  const int wn   = wave & 3;         // 0..3 -> N offset wn*64
  const int bhalf = wn >> 1;
  const int brow0 = (wn & 1) * 64;

  // XCD-aware bijective swizzle (all grids here are %8==0)
  const int nx    = gridDim.x;
  const int lin   = blockIdx.y * nx + blockIdx.x;
  const int total = nx * gridDim.y;
  const int v     = (lin & 7) * (total >> 3) + (lin >> 3);
  const int m0 = (v / nx) << 8;
  const int n0 = (v % nx) << 8;

  const int T = K >> 6;              // K-tiles (>= 3 at all call sites)

  float4v acc[8][4];
#pragma unroll
  for (int i = 0; i < 8; i++)
#pragma unroll
    for (int j = 0; j < 4; j++) acc[i][j] = (float4v){0.f, 0.f, 0.f, 0.f};

  // staging source (per lane)
  const int srow = lane >> 3;
  const int scol = ((lane & 7) ^ srow) << 3;
  const int rowc = wave * 16 + srow;
  const u16* aS = A + (size_t)(m0 + rowc) * K + scol;
  const u16* bS = W + (size_t)(n0 + rowc) * K + scol;

  // LDS byte-address bases for asm ds_reads
  const unsigned laBase = lds_addr(&LA[0][0][0]);
  const unsigned lbBase = lds_addr(&LB[0][0][0]);
  const unsigned sw0 = (unsigned)((quad ^ l7) << 3);
  const unsigned sw1 = (unsigned)(((4 + quad) ^ l7) << 3);
  const unsigned rb  = (unsigned)(l15 * 64);
  const unsigned aW  = laBase + (unsigned)(wm * 16384);
  const unsigned bW  = lbBase + (unsigned)(bhalf * 16384 + brow0 * 128);

  short8 af[4][2];
  short8 bf0[2][2];
  short8 bf1[2][2];

  // ---- prologue: stage t0 and t1 completely (16 loads); drain t0 (leave 8) ----
  STG_A(0, 0, 0); STG_A(0, 1, 0);
  STG_B(0, 0, 0); STG_B(0, 1, 0);
  STG_A(1, 0, 1); STG_A(1, 1, 1);
  STG_B(1, 0, 1); STG_B(1, 1, 1);
  asm volatile("s_waitcnt vmcnt(8)" ::: "memory");
  SBAR();

  for (int kt = 0; kt < T; ++kt) {
    const int buf = kt & 1;
    const unsigned aT = aW + (unsigned)(buf * 32768);
    const unsigned bT = bW + (unsigned)(buf * 32768);
    // -------- phase 1: (M0,N0) --------
    RD_A(0);
    RD_B(bf0, 0);
    SBAR();
    WAITL();
    MM(0, 0, bf0);
    SBAR();
    // -------- phase 2: (M0,N1) --------
    RD_B(bf1, 2);
    SBAR();
    WAITL();
    MM(0, 2, bf1);
    SBAR();
    // -------- phase 3: (M1,N0); re-read A[M1] --------
    RD_A(4);
    SBAR();
    WAITL();
    MM(4, 0, bf0);
    SBAR();
    // -------- phase 4: stage ALL of t+2 (A+B, 8 loads, in place); (M1,N1) --------
    if (kt + 2 < T) {
      STG_A(buf, 0, kt + 2); STG_A(buf, 1, kt + 2);
      STG_B(buf, 0, kt + 2); STG_B(buf, 1, kt + 2);
    }
    SBAR();
    MM(4, 2, bf1);
    if (kt >= T - 2) { asm volatile("s_waitcnt vmcnt(0)" ::: "memory"); }
    else             { asm volatile("s_waitcnt vmcnt(8)" ::: "memory"); }
    SBAR();
  }

  // ---- epilogue ----
#pragma unroll
  for (int mi = 0; mi < 8; ++mi) {
#pragma unroll
    for (int r = 0; r < 4; ++r) {
      const int row = m0 + wm * 128 + mi * 16 + quad * 4 + r;
#pragma unroll
      for (int ni = 0; ni < 4; ++ni) {
        const int col = n0 + wn * 64 + ni * 16 + l15;
        float v2 = acc[mi][ni][r];
        if (EPI == 0) {
          out_bf[(size_t)row * N + col] = f32_to_bf16(v2);
        } else if (EPI == 1) {
          out_bf[(size_t)row * N + col] = f32_to_bf16(gelu_f(v2 + bias[col]));
        } else if (EPI == 2) {
          out_f[(size_t)row * N + col] = 2.0f * (v2 + bias[col]);
        } else {
          out_f[(size_t)row * N + col] = v2 + bias[col] + resid[(size_t)row * N + col];
        }
      }
    }
  }
}

#undef SBAR
#undef WAITL
#undef STG_A
#undef STG_B
#undef RD_A
#undef RD_B
#undef MM

// control arm: proven 128^2 core
__global__ __launch_bounds__(256, 3)
void gemm_qkv(const u16* __restrict__ A, const u16* __restrict__ W, int N, int K,
              u16* __restrict__ out_bf) {
  gemm_core128<0>(A, W, N, K, nullptr, nullptr, out_bf, nullptr);
}
__global__ __launch_bounds__(256, 3)
void gemm_proj2x(const u16* __restrict__ A, const u16* __restrict__ W, int N, int K,
                 const float* __restrict__ bias, float* __restrict__ out_f) {
  gemm_core128<2>(A, W, N, K, bias, nullptr, nullptr, out_f);
}
__global__ __launch_bounds__(256, 3)
void gemm_fc1gelu(const u16* __restrict__ A, const u16* __restrict__ W, int N, int K,
                  const float* __restrict__ bias, u16* __restrict__ out_bf) {
  gemm_core128<1>(A, W, N, K, bias, nullptr, out_bf, nullptr);
}
// treatment arm: 8-phase v3'
__global__ __launch_bounds__(512, 2)
void gemm_fc2res(const u16* __restrict__ A, const u16* __restrict__ W, int N, int K,
                 const float* __restrict__ bias, const float* __restrict__ resid,
                 float* __restrict__ out_f) {
  gemm256_core<3>(A, W, N, K, bias, resid, nullptr, out_f);
}

// ---------------- flash attention v3 ---------------------------------------------
__global__ __launch_bounds__(256)
void attn_kernel(const u16* __restrict__ qkv, const u16* __restrict__ vt,
                 u16* __restrict__ o) {
  __shared__ alignas(16) u16 Ks[64 * 64];
  __shared__ alignas(16) u16 Vs[64 * 64];
  __shared__ alignas(16) u16 Ps[8][16 * 64];
  const int tid  = threadIdx.x;
  const int wave = tid >> 6, lane = tid & 63;
  const int quad = lane >> 4, l15 = lane & 15;
  const int lin = blockIdx.x;
  const int bh = lin % 384, qt = lin / 384;
  const int b = bh / H_, h = bh % H_;
  const size_t rs3 = 3 * C_;

  short8 qf[2][2];
#pragma unroll
  for (int st = 0; st < 2; st++) {
    const int qrow = b * N_ + qt * 128 + st * 64 + wave * 16 + l15;
    const u16* qp = qkv + (size_t)qrow * rs3 + h * D_ + quad * 8;
    qf[st][0] = *(const short8*)qp;
    qf[st][1] = *(const short8*)(qp + 32);
  }

  const int srow = lane >> 3;
  const int gcol = ((lane & 7) ^ srow) * 8;
  const int ch0 = wave * 2, ch1 = wave * 2 + 1;
  const u16* kg0 = qkv + (size_t)(b * N_ + ch0 * 8 + srow) * rs3 + C_ + h * D_ + gcol;
  const u16* kg1 = qkv + (size_t)(b * N_ + ch1 * 8 + srow) * rs3 + C_ + h * D_ + gcol;
  const u16* vg0 = vt + ((size_t)bh * D_ + ch0 * 8 + srow) * N_ + gcol;
  const u16* vg1 = vt + ((size_t)bh * D_ + ch1 * 8 + srow) * N_ + gcol;

  float m[2][4], l[2][4];
  float4v oacc[2][4];
#pragma unroll
  for (int st = 0; st < 2; st++)
#pragma unroll
    for (int r = 0; r < 4; r++) { m[st][r] = -1e30f; l[st][r] = 0.f; }
#pragma unroll
  for (int st = 0; st < 2; st++)
#pragma unroll
    for (int ni = 0; ni < 4; ni++) oacc[st][ni] = (float4v){0.f, 0.f, 0.f, 0.f};

  for (int kt = 0; kt < 8; ++kt) {
    __syncthreads();
    load_lds16(kg0 + (size_t)(kt * 64) * rs3, &Ks[ch0 * 512]);
    load_lds16(kg1 + (size_t)(kt * 64) * rs3, &Ks[ch1 * 512]);
    load_lds16(vg0 + kt * 64, &Vs[ch0 * 512]);
    load_lds16(vg1 + kt * 64, &Vs[ch1 * 512]);
    __syncthreads();

    short8 kf[4][2];
#pragma unroll
    for (int ni = 0; ni < 4; ni++)
#pragma unroll
      for (int ks = 0; ks < 2; ks++)
        kf[ni][ks] = *(const short8*)&Ks[(ni * 16 + l15) * 64 + ((ks * 4 + quad) ^ (l15 & 7)) * 8];

#pragma unroll
    for (int st = 0; st < 2; st++) {
      u16* myPs = Ps[wave * 2 + st];
      float4v s[4];
#pragma unroll
      for (int ni = 0; ni < 4; ni++) {
        s[ni] = (float4v){0.f, 0.f, 0.f, 0.f};
        s[ni] = __builtin_amdgcn_mfma_f32_16x16x32_bf16(qf[st][0], kf[ni][0], s[ni], 0, 0, 0);
        s[ni] = __builtin_amdgcn_mfma_f32_16x16x32_bf16(qf[st][1], kf[ni][1], s[ni], 0, 0, 0);
      }

      float mt[4];
#pragma unroll
      for (int r = 0; r < 4; r++)
        mt[r] = 0.125f * fmaxf(fmaxf(s[0][r], s[1][r]), fmaxf(s[2][r], s[3][r]));
#pragma unroll
      for (int off = 1; off < 16; off <<= 1)
#pragma unroll
        for (int r = 0; r < 4; r++) mt[r] = fmaxf(mt[r], __shfl_xor(mt[r], off));

      float alpha[4], mnew[4], rsum[4];
#pragma unroll
      for (int r = 0; r < 4; r++) {
        mnew[r] = fmaxf(m[st][r], mt[r]);
        alpha[r] = __expf(m[st][r] - mnew[r]);
        rsum[r] = 0.f;
      }
#pragma unroll
      for (int ni = 0; ni < 4; ni++)
#pragma unroll
        for (int r = 0; r < 4; r++) {
          float p = __expf(s[ni][r] * 0.125f - mnew[r]);
          rsum[r] += p;
          const int prow = quad * 4 + r;
          const int g = (ni * 2 + (l15 >> 3)) ^ (prow & 7);
          myPs[prow * 64 + g * 8 + (l15 & 7)] = f32_to_bf16(p);
        }
#pragma unroll
      for (int off = 1; off < 16; off <<= 1)
#pragma unroll
        for (int r = 0; r < 4; r++) rsum[r] += __shfl_xor(rsum[r], off);
#pragma unroll
      for (int r = 0; r < 4; r++) { l[st][r] = l[st][r] * alpha[r] + rsum[r]; m[st][r] = mnew[r]; }
#pragma unroll
      for (int ni = 0; ni < 4; ni++)
#pragma unroll
        for (int r = 0; r < 4; r++) oacc[st][ni][r] *= alpha[r];

#pragma unroll
      for (int ks = 0; ks < 2; ks++) {
        const int g = (ks * 4 + quad) ^ (l15 & 7);
        short8 pf = *(const short8*)&myPs[l15 * 64 + g * 8];
#pragma unroll
        for (int ni = 0; ni < 4; ni++) {
          short8 vf = *(const short8*)&Vs[(ni * 16 + l15) * 64 + ((ks * 4 + quad) ^ (l15 & 7)) * 8];
          oacc[st][ni] = __builtin_amdgcn_mfma_f32_16x16x32_bf16(pf, vf, oacc[st][ni], 0, 0, 0);
        }
      }
    }
  }

#pragma unroll
  for (int st = 0; st < 2; st++) {
    float inv[4];
#pragma unroll
    for (int r = 0; r < 4; r++) inv[r] = 1.0f / l[st][r];
#pragma unroll
    for (int ni = 0; ni < 4; ni++)
#pragma unroll
      for (int r = 0; r < 4; r++) {
        int row = b * N_ + qt * 128 + st * 64 + wave * 16 + quad * 4 + r;
        int col = h * D_ + ni * 16 + l15;
        o[(size_t)row * C_ + col] = f32_to_bf16(oacc[st][ni][r] * inv[r]);
      }
  }
}

// ---------------- launch ----------------
extern "C" void kernel_launch(void* const* d_in, const int* in_sizes, int n_in,
                              void* d_out, int out_size, void* d_ws, size_t ws_size,
                              hipStream_t stream) {
  const float* x      = (const float*)d_in[0];
  const float* ln1_w  = (const float*)d_in[1];
  const float* ln1_b  = (const float*)d_in[2];
  const float* qkv_w  = (const float*)d_in[3];
  const float* proj_w = (const float*)d_in[4];
  const float* proj_b = (const float*)d_in[5];
  const float* ln2_w  = (const float*)d_in[6];
  const float* ln2_b  = (const float*)d_in[7];
  const float* fc1_w  = (const float*)d_in[8];
  const float* fc1_b  = (const float*)d_in[9];
  const float* fc2_w  = (const float*)d_in[10];
  const float* fc2_b  = (const float*)d_in[11];
  float* out = (float*)d_out;

  char* ws = (char*)d_ws;
  size_t off = 0;
  auto alloc = [&](size_t bytes) { void* p = ws + off; off += (bytes + 255) & ~255ull; return p; };
  u16* wqkv  = (u16*)alloc((size_t)3 * C_ * C_ * 2);
  u16* wproj = (u16*)alloc((size_t)C_ * C_ * 2);
  u16* wfc1  = (u16*)alloc((size_t)HID_ * C_ * 2);
  u16* wfc2  = (u16*)alloc((size_t)C_ * HID_ * 2);
  u16* wbase = wqkv;   // wqkv..wfc2 are contiguous (all segment sizes are 256B-multiples)
  u16* regionA = (u16*)alloc((size_t)BN_ * HID_ * 2);  // h | qkv, later o, later act
  float* xnew  = (float*)alloc((size_t)BN_ * C_ * 4);
  u16* h2      = (u16*)alloc((size_t)BN_ * C_ * 2);

  u16* hbuf = regionA;                        // [BN, C]   (dead after QKV)
  u16* qkvb = regionA + (size_t)BN_ * C_;     // [BN, 3C]  (dead after attn)
  u16* obuf = regionA;                        // [BN, C]   overwrites hbuf
  u16* act  = regionA;                        // [BN, HID] overwrites qkv+o
  u16* vtbuf = (u16*)xnew;                    // [B*H, D, N] aliases xnew (dead before proj writes)

  cast4_kernel<<<dim3(NW3_ / 256), 256, 0, stream>>>(qkv_w, proj_w, fc1_w, fc2_w, wbase);

  ln_kernel<<<dim3(BN_), 256, 0, stream>>>(x, ln1_w, ln1_b, hbuf);

  gemm_qkv<<<dim3(3 * C_ / 128, BN_ / 128), 256, 0, stream>>>(hbuf, wqkv, 3 * C_, C_, qkvb);

  transpose_v<<<dim3(N_ / 64, B_ * H_), 256, 0, stream>>>(qkvb, vtbuf);

  attn_kernel<<<dim3((N_ / 128) * B_ * H_), 256, 0, stream>>>(qkvb, vtbuf, obuf);

  gemm_proj2x<<<dim3(C_ / 128, BN_ / 128), 256, 0, stream>>>(obuf, wproj, C_, C_, proj_b, xnew);

  ln_kernel<<<dim3(BN_), 256, 0, stream>>>(xnew, ln2_w, ln2_b, h2);

  gemm_fc1gelu<<<dim3(HID_ / 128, BN_ / 128), 256, 0, stream>>>(h2, wfc1, HID_, C_, fc1_b, act);

  gemm_fc2res<<<dim3(C_ / 256, BN_ / 256), 512, 0, stream>>>(act, wfc2, C_, HID_, fc2_b, xnew, out);
}